// Round 21
// baseline (52.445 us; speedup 1.0000x reference)
//
#include <hip/hip_runtime.h>

#define TQ 512
#define TK 256
#define BB 8
#define CC 128

// 2*log2(e): exp2(SCALE2L2E * x) == e^(2x)
#define SCALE2L2E 2.8853900817779268f
#define L2E 1.4426950408889634f

__device__ __forceinline__ float fexp2(float x) { return __builtin_amdgcn_exp2f(x); }
__device__ __forceinline__ float frcp(float x)  { return __builtin_amdgcn_rcpf(x); }

typedef __fp16 h16x2 __attribute__((ext_vector_type(2)));
typedef __fp16 h16x4 __attribute__((ext_vector_type(4)));
typedef __fp16 h16x8 __attribute__((ext_vector_type(8)));
typedef _Float16 f16x8 __attribute__((ext_vector_type(8)));
typedef float f32x4 __attribute__((ext_vector_type(4)));

__device__ __forceinline__ f16x8 pack8(float4 lo, float4 hi) {
    h16x2 a0 = __builtin_amdgcn_cvt_pkrtz(lo.x, lo.y);
    h16x2 a1 = __builtin_amdgcn_cvt_pkrtz(lo.z, lo.w);
    h16x2 a2 = __builtin_amdgcn_cvt_pkrtz(hi.x, hi.y);
    h16x2 a3 = __builtin_amdgcn_cvt_pkrtz(hi.z, hi.w);
    h16x4 p0 = __builtin_shufflevector(a0, a1, 0, 1, 2, 3);
    h16x4 p1 = __builtin_shufflevector(a2, a3, 0, 1, 2, 3);
    h16x8 r = __builtin_shufflevector(p0, p1, 0, 1, 2, 3, 4, 5, 6, 7);
    return __builtin_bit_cast(f16x8, r);
}

__device__ __forceinline__ h16x4 pack4h(float4 v) {
    h16x2 lo = __builtin_amdgcn_cvt_pkrtz(v.x, v.y);
    h16x2 hi = __builtin_amdgcn_cvt_pkrtz(v.z, v.w);
    return __builtin_shufflevector(lo, hi, 0, 1, 2, 3);
}

// ---------------- Kernel 1: MFMA projections, all conversion in-kernel ------
// Even blocks: KV job. X tile (16x640 fp32) staged -> LDS frag layout
// (group stride 1040B, slot XOR) as verified in round 20. W frags loaded
// fp32 DIRECT from global (row c0+lr, 32B/lane contiguous; 16 segments/instr)
// and packed in-register -> no W16 buffer, no convert kernel.
// Odd blocks: Q job, A/B frags fp32-direct with K=80->96 zero-pad guard.
__global__ __launch_bounds__(256) void proj_mfma(
    const float* __restrict__ k_in, const float* __restrict__ v_in,
    const float* __restrict__ q_in, const float* __restrict__ Wk,
    const float* __restrict__ Wv, const float* __restrict__ Wq,
    float* __restrict__ eqp, float* __restrict__ ekp, _Float16* __restrict__ v16s)
{
    __shared__ _Float16 xs[20 * 520];              // 20 groups x 1040B

    const int tid = threadIdx.x;
    const int w = tid >> 6;
    const int l = tid & 63;
    const int lr = l & 15, lk = l >> 4;
    const int id = blockIdx.x;
    const int j = (id >> 1) * 4 + w;               // job id 0..1023

    f32x4 acc0 = {0.f, 0.f, 0.f, 0.f};
    f32x4 acc1 = {0.f, 0.f, 0.f, 0.f};

    if ((id & 1) == 0) {
        // ---- KV job: 4 waves share one (tensor, rtile); wave = c-tile pair ----
        const int tensor = j >> 9;                 // 0: keys, 1: values
        const int jj = j & 511;
        const int rtile = jj >> 2;
        const int c0 = (jj & 3) * 32;
        const int r0 = rtile * 16;
        const float* __restrict__ X = tensor ? v_in : k_in;
        const float* __restrict__ Wf = tensor ? Wv : Wk;

        // stage X tile -> LDS frags (coalesced fp32 reads, cvt, scatter-write)
        for (int i = tid; i < 2560; i += 256) {
            const int r = i / 160, kq = i % 160;
            float4 v = *(const float4*)&X[(size_t)(r0 + r) * 640 + kq * 4];
            const int k0 = kq * 4;
            const int s = k0 >> 5;
            const int lkw = (k0 >> 3) & 3;
            const int jh = (k0 >> 2) & 1;
            const int slot = (lkw * 16 + r) ^ lkw;
            *(h16x4*)((char*)xs + s * 1040 + slot * 16 + jh * 8) = pack4h(v);
        }
        __syncthreads();

        const int sigma = l ^ ((l >> 4) & 3);
        const char* __restrict__ Abase = (const char*)xs + sigma * 16;
        const float* __restrict__ W0p = Wf + (size_t)(c0 + lr) * 640 + lk * 8;
        const float* __restrict__ W1p = W0p + 16 * 640;

        float4 wl0[2], wh0[2], wl1[2], wh1[2];
        wl0[0] = *(const float4*)W0p;        wh0[0] = *(const float4*)(W0p + 4);
        wl1[0] = *(const float4*)W1p;        wh1[0] = *(const float4*)(W1p + 4);
        wl0[1] = *(const float4*)(W0p + 32); wh0[1] = *(const float4*)(W0p + 36);
        wl1[1] = *(const float4*)(W1p + 32); wh1[1] = *(const float4*)(W1p + 36);

#pragma unroll
        for (int s = 0; s < 20; ++s) {
            const int cur = s & 1;
            f16x8 a = *(const f16x8*)(Abase + s * 1040);
            f16x8 b0 = pack8(wl0[cur], wh0[cur]);
            f16x8 b1 = pack8(wl1[cur], wh1[cur]);
            if (s + 2 < 20) {
                wl0[cur] = *(const float4*)(W0p + (s + 2) * 32);
                wh0[cur] = *(const float4*)(W0p + (s + 2) * 32 + 4);
                wl1[cur] = *(const float4*)(W1p + (s + 2) * 32);
                wh1[cur] = *(const float4*)(W1p + (s + 2) * 32 + 4);
            }
            acc0 = __builtin_amdgcn_mfma_f32_16x16x32_f16(a, b0, acc0, 0, 0, 0);
            acc1 = __builtin_amdgcn_mfma_f32_16x16x32_f16(a, b1, acc1, 0, 0, 0);
        }

        if (tensor == 0) {                          // ekp [b][c][t], Ek = e^{2k}
#pragma unroll
            for (int jr = 0; jr < 4; ++jr) {
                int r = r0 + lk * 4 + jr;
                int t = r >> 3, bt = r & 7;
                ekp[((size_t)bt * CC + c0 + lr) * TK + t] = fexp2(SCALE2L2E * acc0[jr]);
                ekp[((size_t)bt * CC + c0 + 16 + lr) * TK + t] = fexp2(SCALE2L2E * acc1[jr]);
            }
        } else {                                    // v16s frag-linear
#pragma unroll
            for (int jr = 0; jr < 4; ++jr) {
                int r = r0 + lk * 4 + jr;
                int t = r >> 3, bt = r & 7;
                int base = bt * 32768 + (t >> 5) * 512 + ((t >> 3) & 3) * 128
                         + lr * 8 + (t & 7);
                v16s[base + (c0 >> 4) * 4096] = (_Float16)acc0[jr];
                v16s[base + ((c0 >> 4) + 1) * 4096] = (_Float16)acc1[jr];
            }
        }
    } else {
        // ---- Q job: A/B frags fp32-direct with zero-pad (K=80 -> 96) ----
        const int rtile = j >> 2;
        const int c0 = (j & 3) * 32;

        const float* __restrict__ Ap = q_in + (size_t)(rtile * 16 + lr) * 80 + lk * 8;
        const float* __restrict__ B0p = Wq + (size_t)(c0 + lr) * 80 + lk * 8;
        const float* __restrict__ B1p = B0p + 16 * 80;
        const f16x8 zero = {};

#pragma unroll
        for (int s = 0; s < 3; ++s) {
            const bool live = (s < 2) || (lk < 2);
            f16x8 a = zero, b0 = zero, b1 = zero;
            if (live) {
                a  = pack8(*(const float4*)(Ap + s * 32),
                           *(const float4*)(Ap + s * 32 + 4));
                b0 = pack8(*(const float4*)(B0p + s * 32),
                           *(const float4*)(B0p + s * 32 + 4));
                b1 = pack8(*(const float4*)(B1p + s * 32),
                           *(const float4*)(B1p + s * 32 + 4));
            }
            acc0 = __builtin_amdgcn_mfma_f32_16x16x32_f16(a, b0, acc0, 0, 0, 0);
            acc1 = __builtin_amdgcn_mfma_f32_16x16x32_f16(a, b1, acc1, 0, 0, 0);
        }

#pragma unroll
        for (int jr = 0; jr < 4; ++jr) {            // eqp [b][t][c], Eq = e^{2q}
            int r = rtile * 16 + lk * 4 + jr;
            int t = r >> 3, bt = r & 7;
            eqp[((size_t)bt * TQ + t) * CC + c0 + lr] = fexp2(SCALE2L2E * acc0[jr]);
            eqp[((size_t)bt * TQ + t) * CC + c0 + 16 + lr] = fexp2(SCALE2L2E * acc1[jr]);
        }
    }
}

// ---------------- Kernel 2: fused scores + softmax + PV (c-quarter split) ---
__global__ __launch_bounds__(1024, 1) void attn_pv_kernel(
    const float* __restrict__ eqp, const float* __restrict__ ekp,
    const float* __restrict__ Wvec, const _Float16* __restrict__ v16s,
    float* __restrict__ attn_out, float* __restrict__ out)
{
    __shared__ float pa[4][64][52];     // [g][lane][3 quarters x 16 floats]
    __shared__ _Float16 pl[16][264];

    const int tid = threadIdx.x;
    const int lane = tid & 63;
    const int w = __builtin_amdgcn_readfirstlane(tid >> 6);   // 0..15
    const int g = w >> 2;                                     // row-group 0..3
    const int qrt = w & 3;                                    // c-quarter
    const int b = blockIdx.y;
    const int q0g = blockIdx.x * 16;
    const int q0 = q0g + g * 4;

    const float* __restrict__ qr0 = eqp + ((size_t)b * TQ + q0) * CC + qrt * 32;
    const float* __restrict__ qr1 = qr0 + CC;
    const float* __restrict__ qr2 = qr1 + CC;
    const float* __restrict__ qr3 = qr2 + CC;
    const float* __restrict__ kb = ekp + (size_t)b * CC * TK + (qrt * 32) * TK + lane * 4;
    const float* __restrict__ wvp = Wvec + qrt * 32;

    float sw = Wvec[lane] + Wvec[64 + lane];
#pragma unroll
    for (int m = 32; m >= 1; m >>= 1) sw += __shfl_xor(sw, m, 64);

    float a0[4] = {0.f, 0.f, 0.f, 0.f};
    float a1[4] = {0.f, 0.f, 0.f, 0.f};
    float a2[4] = {0.f, 0.f, 0.f, 0.f};
    float a3[4] = {0.f, 0.f, 0.f, 0.f};

    float4 k0 = *(const float4*)&kb[0 * TK];
    float4 k1 = *(const float4*)&kb[1 * TK];
    float4 k2 = *(const float4*)&kb[2 * TK];
    float4 k3 = *(const float4*)&kb[3 * TK];
    float4 wv = *(const float4*)&wvp[0];
    float4 qa = *(const float4*)&qr0[0];
    float4 qb = *(const float4*)&qr1[0];
    float4 qc = *(const float4*)&qr2[0];
    float4 qd = *(const float4*)&qr3[0];

    for (int c4 = 0; c4 < 32; c4 += 4) {
        float4 n0, n1, n2, n3, nwv, nqa, nqb, nqc, nqd;
        if (c4 + 4 < 32) {
            n0 = *(const float4*)&kb[(c4 + 4) * TK];
            n1 = *(const float4*)&kb[(c4 + 5) * TK];
            n2 = *(const float4*)&kb[(c4 + 6) * TK];
            n3 = *(const float4*)&kb[(c4 + 7) * TK];
            nwv = *(const float4*)&wvp[c4 + 4];
            nqa = *(const float4*)&qr0[c4 + 4];
            nqb = *(const float4*)&qr1[c4 + 4];
            nqc = *(const float4*)&qr2[c4 + 4];
            nqd = *(const float4*)&qr3[c4 + 4];
        }
#define CCOMP(KF, WW, EA, EB, EC, ED)                                   \
        a0[0] = fmaf(WW, frcp(fmaf(EA, KF.x, 1.f)), a0[0]);             \
        a0[1] = fmaf(WW, frcp(fmaf(EA, KF.y, 1.f)), a0[1]);             \
        a0[2] = fmaf(WW, frcp(fmaf(EA, KF.z, 1.f)), a0[2]);             \
        a0[3] = fmaf(WW, frcp(fmaf(EA, KF.w, 1.f)), a0[3]);             \
        a1[0] = fmaf(WW, frcp(fmaf(EB, KF.x, 1.f)), a1[0]);             \
        a1[1] = fmaf(WW, frcp(fmaf(EB, KF.y, 1.f)), a1[1]);             \
        a1[2] = fmaf(WW, frcp(fmaf(EB, KF.z, 1.f)), a1[2]);             \
        a1[3] = fmaf(WW, frcp(fmaf(EB, KF.w, 1.f)), a1[3]);             \
        a2[0] = fmaf(WW, frcp(fmaf(EC, KF.x, 1.f)), a2[0]);             \
        a2[1] = fmaf(WW, frcp(fmaf(EC, KF.y, 1.f)), a2[1]);             \
        a2[2] = fmaf(WW, frcp(fmaf(EC, KF.z, 1.f)), a2[2]);             \
        a2[3] = fmaf(WW, frcp(fmaf(EC, KF.w, 1.f)), a2[3]);             \
        a3[0] = fmaf(WW, frcp(fmaf(ED, KF.x, 1.f)), a3[0]);             \
        a3[1] = fmaf(WW, frcp(fmaf(ED, KF.y, 1.f)), a3[1]);             \
        a3[2] = fmaf(WW, frcp(fmaf(ED, KF.z, 1.f)), a3[2]);             \
        a3[3] = fmaf(WW, frcp(fmaf(ED, KF.w, 1.f)), a3[3]);
        CCOMP(k0, wv.x, qa.x, qb.x, qc.x, qd.x)
        CCOMP(k1, wv.y, qa.y, qb.y, qc.y, qd.y)
        CCOMP(k2, wv.z, qa.z, qb.z, qc.z, qd.z)
        CCOMP(k3, wv.w, qa.w, qb.w, qc.w, qd.w)
#undef CCOMP
        k0 = n0; k1 = n1; k2 = n2; k3 = n3;
        wv = nwv; qa = nqa; qb = nqb; qc = nqc; qd = nqd;
    }

    // quarters 1-3 publish partials
    if (qrt != 0) {
        float* dstp = &pa[g][lane][(qrt - 1) * 16];
        *(float4*)(dstp + 0)  = make_float4(a0[0], a0[1], a0[2], a0[3]);
        *(float4*)(dstp + 4)  = make_float4(a1[0], a1[1], a1[2], a1[3]);
        *(float4*)(dstp + 8)  = make_float4(a2[0], a2[1], a2[2], a2[3]);
        *(float4*)(dstp + 12) = make_float4(a3[0], a3[1], a3[2], a3[3]);
    }
    __syncthreads();

    if (qrt == 0) {
#pragma unroll
        for (int p = 0; p < 3; ++p) {
            const float* srcp = &pa[g][lane][p * 16];
            float4 x0 = *(const float4*)(srcp + 0);
            float4 x1 = *(const float4*)(srcp + 4);
            float4 x2 = *(const float4*)(srcp + 8);
            float4 x3 = *(const float4*)(srcp + 12);
            a0[0] += x0.x; a0[1] += x0.y; a0[2] += x0.z; a0[3] += x0.w;
            a1[0] += x1.x; a1[1] += x1.y; a1[2] += x1.z; a1[3] += x1.w;
            a2[0] += x2.x; a2[1] += x2.y; a2[2] += x2.z; a2[3] += x2.w;
            a3[0] += x3.x; a3[1] += x3.y; a3[2] += x3.z; a3[3] += x3.w;
        }

        float sc0[4], sc1[4], sc2[4], sc3[4];
#pragma unroll
        for (int j = 0; j < 4; ++j) {
            sc0[j] = sw - 2.f * a0[j];
            sc1[j] = sw - 2.f * a1[j];
            sc2[j] = sw - 2.f * a2[j];
            sc3[j] = sw - 2.f * a3[j];
        }

        float m0 = fmaxf(fmaxf(sc0[0], sc0[1]), fmaxf(sc0[2], sc0[3]));
        float m1 = fmaxf(fmaxf(sc1[0], sc1[1]), fmaxf(sc1[2], sc1[3]));
        float m2 = fmaxf(fmaxf(sc2[0], sc2[1]), fmaxf(sc2[2], sc2[3]));
        float m3 = fmaxf(fmaxf(sc3[0], sc3[1]), fmaxf(sc3[2], sc3[3]));
#pragma unroll
        for (int m = 32; m >= 1; m >>= 1) {
            m0 = fmaxf(m0, __shfl_xor(m0, m, 64));
            m1 = fmaxf(m1, __shfl_xor(m1, m, 64));
            m2 = fmaxf(m2, __shfl_xor(m2, m, 64));
            m3 = fmaxf(m3, __shfl_xor(m3, m, 64));
        }
        float e0[4], e1[4], e2[4], e3[4];
        float s0 = 0.f, s1 = 0.f, s2 = 0.f, s3 = 0.f;
#pragma unroll
        for (int j = 0; j < 4; ++j) {
            e0[j] = fexp2((sc0[j] - m0) * L2E); s0 += e0[j];
            e1[j] = fexp2((sc1[j] - m1) * L2E); s1 += e1[j];
            e2[j] = fexp2((sc2[j] - m2) * L2E); s2 += e2[j];
            e3[j] = fexp2((sc3[j] - m3) * L2E); s3 += e3[j];
        }
#pragma unroll
        for (int m = 32; m >= 1; m >>= 1) {
            s0 += __shfl_xor(s0, m, 64);
            s1 += __shfl_xor(s1, m, 64);
            s2 += __shfl_xor(s2, m, 64);
            s3 += __shfl_xor(s3, m, 64);
        }
        const float r0 = frcp(s0), r1 = frcp(s1), r2 = frcp(s2), r3 = frcp(s3);

        const float4 p0 = make_float4(e0[0] * r0, e0[1] * r0, e0[2] * r0, e0[3] * r0);
        const float4 p1 = make_float4(e1[0] * r1, e1[1] * r1, e1[2] * r1, e1[3] * r1);
        const float4 p2 = make_float4(e2[0] * r2, e2[1] * r2, e2[2] * r2, e2[3] * r2);
        const float4 p3 = make_float4(e3[0] * r3, e3[1] * r3, e3[2] * r3, e3[3] * r3);

        float* __restrict__ po = attn_out + ((size_t)b * TQ + q0) * TK + lane * 4;
        *(float4*)(po + 0 * TK) = p0;
        *(float4*)(po + 1 * TK) = p1;
        *(float4*)(po + 2 * TK) = p2;
        *(float4*)(po + 3 * TK) = p3;

        *(h16x4*)&pl[g * 4 + 0][lane * 4] = pack4h(p0);
        *(h16x4*)&pl[g * 4 + 1][lane * 4] = pack4h(p1);
        *(h16x4*)&pl[g * 4 + 2][lane * 4] = pack4h(p2);
        *(h16x4*)&pl[g * 4 + 3][lane * 4] = pack4h(p3);
    }
    __syncthreads();

    // ---- PV: waves 0-7 -> c-tile w ----
    if (w < 8) {
        const int lr = lane & 15, lk = lane >> 4;
        const _Float16* __restrict__ Vr = v16s + b * 32768 + w * 4096 + lane * 8;
        f32x4 acc = {0.f, 0.f, 0.f, 0.f};
#pragma unroll
        for (int s = 0; s < 8; ++s) {
            f16x8 a = *(const f16x8*)&pl[lr][s * 32 + lk * 8];
            f16x8 bv = *(const f16x8*)(Vr + s * 512);
            acc = __builtin_amdgcn_mfma_f32_16x16x32_f16(a, bv, acc, 0, 0, 0);
        }
        float4 o = make_float4(acc[0], acc[1], acc[2], acc[3]);
        *(float4*)&out[((size_t)b * CC + w * 16 + lr) * TQ + q0g + lk * 4] = o;
    }
}

extern "C" void kernel_launch(void* const* d_in, const int* in_sizes, int n_in,
                              void* d_out, int out_size, void* d_ws, size_t ws_size,
                              hipStream_t stream) {
    const float* queries = (const float*)d_in[0];
    const float* keys    = (const float*)d_in[1];
    const float* values  = (const float*)d_in[2];
    const float* Wq      = (const float*)d_in[3];
    const float* Wk      = (const float*)d_in[4];
    const float* Wv      = (const float*)d_in[5];
    const float* Wvec    = (const float*)d_in[6];

    float* out  = (float*)d_out;                 // (8,128,512)
    float* attn = out + BB * CC * TQ;            // (8,512,256)

    float* ws = (float*)d_ws;
    float* eqp = ws;                              // [b][t][c] 4096*128 f32
    float* ekp = eqp + 4096 * CC;                 // [b][c][t] 2048*128 f32
    _Float16* v16s = (_Float16*)(ekp + 2048 * CC);// frag-linear 8*32768

    proj_mfma<<<dim3(512), 256, 0, stream>>>(
        keys, values, queries, Wk, Wv, Wq, eqp, ekp, v16s);
    attn_pv_kernel<<<dim3(32, 8), 1024, 0, stream>>>(
        eqp, ekp, Wvec, v16s, attn, out);
}

// Round 22
// 40.745 us; speedup vs baseline: 1.2871x; 1.2871x over previous
//
#include <hip/hip_runtime.h>

#define TQ 512
#define TK 256
#define BB 8
#define CC 128

// 2*log2(e): exp2(SCALE2L2E * x) == e^(2x)
#define SCALE2L2E 2.8853900817779268f
#define L2E 1.4426950408889634f

__device__ __forceinline__ float fexp2(float x) { return __builtin_amdgcn_exp2f(x); }
__device__ __forceinline__ float frcp(float x)  { return __builtin_amdgcn_rcpf(x); }

typedef __fp16 h16x2 __attribute__((ext_vector_type(2)));
typedef __fp16 h16x4 __attribute__((ext_vector_type(4)));
typedef __fp16 h16x8 __attribute__((ext_vector_type(8)));
typedef _Float16 f16x8 __attribute__((ext_vector_type(8)));
typedef float f32x4 __attribute__((ext_vector_type(4)));

__device__ __forceinline__ f16x8 pack8(float4 lo, float4 hi) {
    h16x2 a0 = __builtin_amdgcn_cvt_pkrtz(lo.x, lo.y);
    h16x2 a1 = __builtin_amdgcn_cvt_pkrtz(lo.z, lo.w);
    h16x2 a2 = __builtin_amdgcn_cvt_pkrtz(hi.x, hi.y);
    h16x2 a3 = __builtin_amdgcn_cvt_pkrtz(hi.z, hi.w);
    h16x4 p0 = __builtin_shufflevector(a0, a1, 0, 1, 2, 3);
    h16x4 p1 = __builtin_shufflevector(a2, a3, 0, 1, 2, 3);
    h16x8 r = __builtin_shufflevector(p0, p1, 0, 1, 2, 3, 4, 5, 6, 7);
    return __builtin_bit_cast(f16x8, r);
}

__device__ __forceinline__ h16x4 pack4h(float4 v) {
    h16x2 lo = __builtin_amdgcn_cvt_pkrtz(v.x, v.y);
    h16x2 hi = __builtin_amdgcn_cvt_pkrtz(v.z, v.w);
    return __builtin_shufflevector(lo, hi, 0, 1, 2, 3);
}

// Frag-linear layout: [tile][step][lane 64][8 halfs]; frag (s,l) holds
// M[tile*16 + (l&15)][s*32 + (l>>4)*8 + j].
#define CWK 10240
#define CWV 10240
#define CWQ 1536
#define CXQ 49152
#define CXK 163840
#define CXV 163840
#define CTOT (CWK + CWV + CWQ + CXQ + CXK + CXV)   // 398848

// ---------------- Kernel 0: convert + swizzle to frag-linear ----------------
__global__ __launch_bounds__(256) void convert_kernel(
    const float* __restrict__ Wk, const float* __restrict__ Wv,
    const float* __restrict__ Wq, const float* __restrict__ q_in,
    const float* __restrict__ k_in, const float* __restrict__ v_in,
    f16x8* __restrict__ Wk16s, f16x8* __restrict__ Wv16s,
    f16x8* __restrict__ Wq16s, f16x8* __restrict__ Xq16s,
    f16x8* __restrict__ Xk16s, f16x8* __restrict__ Xv16s)
{
    const int d = blockIdx.x * 256 + threadIdx.x;
    if (d >= CTOT) return;
    const f16x8 zero = {};

    const float* __restrict__ src;
    f16x8* __restrict__ dst;
    int dd, K;
    if (d < CWK)                         { dd = d; src = Wk; dst = Wk16s; K = 640; }
    else if (d < CWK + CWV)              { dd = d - CWK; src = Wv; dst = Wv16s; K = 640; }
    else if (d < CWK + CWV + CWQ)        { dd = d - CWK - CWV; src = Wq; dst = Wq16s; K = 80; }
    else if (d < CWK + CWV + CWQ + CXQ)  { dd = d - CWK - CWV - CWQ; src = q_in; dst = Xq16s; K = 80; }
    else if (d < CTOT - CXV)             { dd = d - CWK - CWV - CWQ - CXQ; src = k_in; dst = Xk16s; K = 640; }
    else                                 { dd = d - (CTOT - CXV); src = v_in; dst = Xv16s; K = 640; }

    const int nstep = (K == 640) ? 20 : 3;
    const int per = nstep * 64;
    const int tile = dd / per, rem = dd % per;
    const int s = rem >> 6, l = rem & 63;
    const int lr = l & 15, lk = l >> 4;
    const int r = tile * 16 + lr, k0 = s * 32 + lk * 8;
    if (K == 80 && k0 >= 80) { dst[dd] = zero; return; }
    float4 lo = *(const float4*)&src[(size_t)r * K + k0];
    float4 hi = *(const float4*)&src[(size_t)r * K + k0 + 4];
    dst[dd] = pack8(lo, hi);
}

// ---------------- Kernel 1: MFMA projections (all-frag-linear) --------------
__global__ __launch_bounds__(256) void proj_mfma(
    const _Float16* __restrict__ Wk16s, const _Float16* __restrict__ Wv16s,
    const _Float16* __restrict__ Wq16s, const _Float16* __restrict__ Xq16s,
    const _Float16* __restrict__ Xk16s, const _Float16* __restrict__ Xv16s,
    float* __restrict__ eqp, float* __restrict__ ekp, _Float16* __restrict__ v16s)
{
    const int tid = threadIdx.x;
    const int w = tid >> 6;
    const int l = tid & 63;
    const int lr = l & 15, lk = l >> 4;
    const int id = blockIdx.x;
    const int j = (id >> 1) * 4 + w;               // job id 0..1023

    f32x4 acc0 = {0.f, 0.f, 0.f, 0.f};
    f32x4 acc1 = {0.f, 0.f, 0.f, 0.f};

    if ((id & 1) == 0) {
        // ---- KV job ----
        const int tensor = j >> 9;                 // 0: keys, 1: values
        const int jj = j & 511;
        const int rtile = jj >> 2;
        const int c0 = (jj & 3) * 32;
        const int r0 = rtile * 16;
        const _Float16* __restrict__ Xs = tensor ? Xv16s : Xk16s;
        const _Float16* __restrict__ Wt = tensor ? Wv16s : Wk16s;

        const _Float16* __restrict__ A0 = Xs + (size_t)rtile * 10240 + l * 8;
        const _Float16* __restrict__ B0 = Wt + (c0 >> 4) * 10240 + l * 8;
        const _Float16* __restrict__ B1 = B0 + 10240;

#pragma unroll
        for (int s = 0; s < 20; ++s) {
            f16x8 a = *(const f16x8*)(A0 + s * 512);
            f16x8 b0 = *(const f16x8*)(B0 + s * 512);
            f16x8 b1 = *(const f16x8*)(B1 + s * 512);
            acc0 = __builtin_amdgcn_mfma_f32_16x16x32_f16(a, b0, acc0, 0, 0, 0);
            acc1 = __builtin_amdgcn_mfma_f32_16x16x32_f16(a, b1, acc1, 0, 0, 0);
        }

        if (tensor == 0) {                          // ekp [b][c][t], Ek = e^{2k}
#pragma unroll
            for (int jr = 0; jr < 4; ++jr) {
                int r = r0 + lk * 4 + jr;
                int t = r >> 3, bt = r & 7;
                ekp[((size_t)bt * CC + c0 + lr) * TK + t] = fexp2(SCALE2L2E * acc0[jr]);
                ekp[((size_t)bt * CC + c0 + 16 + lr) * TK + t] = fexp2(SCALE2L2E * acc1[jr]);
            }
        } else {                                    // v16s frag-linear
#pragma unroll
            for (int jr = 0; jr < 4; ++jr) {
                int r = r0 + lk * 4 + jr;
                int t = r >> 3, bt = r & 7;
                int base = bt * 32768 + (t >> 5) * 512 + ((t >> 3) & 3) * 128
                         + lr * 8 + (t & 7);
                v16s[base + (c0 >> 4) * 4096] = (_Float16)acc0[jr];
                v16s[base + ((c0 >> 4) + 1) * 4096] = (_Float16)acc1[jr];
            }
        }
    } else {
        // ---- Q job ----
        const int rtile = j >> 2;
        const int c0 = (j & 3) * 32;

        const _Float16* __restrict__ A0 = Xq16s + (size_t)rtile * 1536 + l * 8;
        const _Float16* __restrict__ B0 = Wq16s + (c0 >> 4) * 1536 + l * 8;
        const _Float16* __restrict__ B1 = B0 + 1536;

#pragma unroll
        for (int s = 0; s < 3; ++s) {
            f16x8 a = *(const f16x8*)(A0 + s * 512);
            f16x8 bb0 = *(const f16x8*)(B0 + s * 512);
            f16x8 bb1 = *(const f16x8*)(B1 + s * 512);
            acc0 = __builtin_amdgcn_mfma_f32_16x16x32_f16(a, bb0, acc0, 0, 0, 0);
            acc1 = __builtin_amdgcn_mfma_f32_16x16x32_f16(a, bb1, acc1, 0, 0, 0);
        }

#pragma unroll
        for (int jr = 0; jr < 4; ++jr) {            // eqp [b][t][c], Eq = e^{2q}
            int r = rtile * 16 + lk * 4 + jr;
            int t = r >> 3, bt = r & 7;
            eqp[((size_t)bt * TQ + t) * CC + c0 + lr] = fexp2(SCALE2L2E * acc0[jr]);
            eqp[((size_t)bt * TQ + t) * CC + c0 + 16 + lr] = fexp2(SCALE2L2E * acc1[jr]);
        }
    }
}

// ---------------- Kernel 2: fused scores + softmax + PV (c-split) -----------
// Block = 512 thr (8 waves) per (16 q-rows, batch). Wave = (row-group g, c-half h).
__global__ __launch_bounds__(512, 2) void attn_pv_kernel(
    const float* __restrict__ eqp, const float* __restrict__ ekp,
    const float* __restrict__ Wvec, const _Float16* __restrict__ v16s,
    float* __restrict__ attn_out, float* __restrict__ out)
{
    __shared__ float pa[4][64][17];
    __shared__ _Float16 pl[16][264];

    const int tid = threadIdx.x;
    const int lane = tid & 63;
    const int w = __builtin_amdgcn_readfirstlane(tid >> 6);   // 0..7
    const int g = w >> 1;                                     // row-group 0..3
    const int h = w & 1;                                      // c-half
    const int b = blockIdx.y;
    const int q0g = blockIdx.x * 16;
    const int q0 = q0g + g * 4;

    const float* __restrict__ qr0 = eqp + ((size_t)b * TQ + q0) * CC + h * 64;
    const float* __restrict__ qr1 = qr0 + CC;
    const float* __restrict__ qr2 = qr1 + CC;
    const float* __restrict__ qr3 = qr2 + CC;
    const float* __restrict__ kb = ekp + (size_t)b * CC * TK + (h * 64) * TK + lane * 4;
    const float* __restrict__ wvp = Wvec + h * 64;

    float sw = Wvec[lane] + Wvec[64 + lane];
#pragma unroll
    for (int m = 32; m >= 1; m >>= 1) sw += __shfl_xor(sw, m, 64);

    float a0[4] = {0.f, 0.f, 0.f, 0.f};
    float a1[4] = {0.f, 0.f, 0.f, 0.f};
    float a2[4] = {0.f, 0.f, 0.f, 0.f};
    float a3[4] = {0.f, 0.f, 0.f, 0.f};

    float4 k0 = *(const float4*)&kb[0 * TK];
    float4 k1 = *(const float4*)&kb[1 * TK];
    float4 k2 = *(const float4*)&kb[2 * TK];
    float4 k3 = *(const float4*)&kb[3 * TK];
    float4 wv = *(const float4*)&wvp[0];
    float4 qa = *(const float4*)&qr0[0];
    float4 qb = *(const float4*)&qr1[0];
    float4 qc = *(const float4*)&qr2[0];
    float4 qd = *(const float4*)&qr3[0];

    for (int c4 = 0; c4 < 64; c4 += 4) {
        float4 n0, n1, n2, n3, nwv, nqa, nqb, nqc, nqd;
        if (c4 + 4 < 64) {
            n0 = *(const float4*)&kb[(c4 + 4) * TK];
            n1 = *(const float4*)&kb[(c4 + 5) * TK];
            n2 = *(const float4*)&kb[(c4 + 6) * TK];
            n3 = *(const float4*)&kb[(c4 + 7) * TK];
            nwv = *(const float4*)&wvp[c4 + 4];
            nqa = *(const float4*)&qr0[c4 + 4];
            nqb = *(const float4*)&qr1[c4 + 4];
            nqc = *(const float4*)&qr2[c4 + 4];
            nqd = *(const float4*)&qr3[c4 + 4];
        }
#define CCOMP(KF, WW, EA, EB, EC, ED)                                   \
        a0[0] = fmaf(WW, frcp(fmaf(EA, KF.x, 1.f)), a0[0]);             \
        a0[1] = fmaf(WW, frcp(fmaf(EA, KF.y, 1.f)), a0[1]);             \
        a0[2] = fmaf(WW, frcp(fmaf(EA, KF.z, 1.f)), a0[2]);             \
        a0[3] = fmaf(WW, frcp(fmaf(EA, KF.w, 1.f)), a0[3]);             \
        a1[0] = fmaf(WW, frcp(fmaf(EB, KF.x, 1.f)), a1[0]);             \
        a1[1] = fmaf(WW, frcp(fmaf(EB, KF.y, 1.f)), a1[1]);             \
        a1[2] = fmaf(WW, frcp(fmaf(EB, KF.z, 1.f)), a1[2]);             \
        a1[3] = fmaf(WW, frcp(fmaf(EB, KF.w, 1.f)), a1[3]);             \
        a2[0] = fmaf(WW, frcp(fmaf(EC, KF.x, 1.f)), a2[0]);             \
        a2[1] = fmaf(WW, frcp(fmaf(EC, KF.y, 1.f)), a2[1]);             \
        a2[2] = fmaf(WW, frcp(fmaf(EC, KF.z, 1.f)), a2[2]);             \
        a2[3] = fmaf(WW, frcp(fmaf(EC, KF.w, 1.f)), a2[3]);             \
        a3[0] = fmaf(WW, frcp(fmaf(ED, KF.x, 1.f)), a3[0]);             \
        a3[1] = fmaf(WW, frcp(fmaf(ED, KF.y, 1.f)), a3[1]);             \
        a3[2] = fmaf(WW, frcp(fmaf(ED, KF.z, 1.f)), a3[2]);             \
        a3[3] = fmaf(WW, frcp(fmaf(ED, KF.w, 1.f)), a3[3]);
        CCOMP(k0, wv.x, qa.x, qb.x, qc.x, qd.x)
        CCOMP(k1, wv.y, qa.y, qb.y, qc.y, qd.y)
        CCOMP(k2, wv.z, qa.z, qb.z, qc.z, qd.z)
        CCOMP(k3, wv.w, qa.w, qb.w, qc.w, qd.w)
#undef CCOMP
        k0 = n0; k1 = n1; k2 = n2; k3 = n3;
        wv = nwv; qa = nqa; qb = nqb; qc = nqc; qd = nqd;
    }

    // h=1 waves publish partials (pitch 17 -> 2 lanes/bank, conflict-free)
    if (h == 1) {
#pragma unroll
        for (int jj = 0; jj < 4; ++jj) {
            pa[g][lane][jj]      = a0[jj];
            pa[g][lane][4 + jj]  = a1[jj];
            pa[g][lane][8 + jj]  = a2[jj];
            pa[g][lane][12 + jj] = a3[jj];
        }
    }
    __syncthreads();

    if (h == 0) {
#pragma unroll
        for (int jj = 0; jj < 4; ++jj) {
            a0[jj] += pa[g][lane][jj];
            a1[jj] += pa[g][lane][4 + jj];
            a2[jj] += pa[g][lane][8 + jj];
            a3[jj] += pa[g][lane][12 + jj];
        }

        float sc0[4], sc1[4], sc2[4], sc3[4];
#pragma unroll
        for (int j = 0; j < 4; ++j) {
            sc0[j] = sw - 2.f * a0[j];
            sc1[j] = sw - 2.f * a1[j];
            sc2[j] = sw - 2.f * a2[j];
            sc3[j] = sw - 2.f * a3[j];
        }

        float m0 = fmaxf(fmaxf(sc0[0], sc0[1]), fmaxf(sc0[2], sc0[3]));
        float m1 = fmaxf(fmaxf(sc1[0], sc1[1]), fmaxf(sc1[2], sc1[3]));
        float m2 = fmaxf(fmaxf(sc2[0], sc2[1]), fmaxf(sc2[2], sc2[3]));
        float m3 = fmaxf(fmaxf(sc3[0], sc3[1]), fmaxf(sc3[2], sc3[3]));
#pragma unroll
        for (int m = 32; m >= 1; m >>= 1) {
            m0 = fmaxf(m0, __shfl_xor(m0, m, 64));
            m1 = fmaxf(m1, __shfl_xor(m1, m, 64));
            m2 = fmaxf(m2, __shfl_xor(m2, m, 64));
            m3 = fmaxf(m3, __shfl_xor(m3, m, 64));
        }
        float e0[4], e1[4], e2[4], e3[4];
        float s0 = 0.f, s1 = 0.f, s2 = 0.f, s3 = 0.f;
#pragma unroll
        for (int j = 0; j < 4; ++j) {
            e0[j] = fexp2((sc0[j] - m0) * L2E); s0 += e0[j];
            e1[j] = fexp2((sc1[j] - m1) * L2E); s1 += e1[j];
            e2[j] = fexp2((sc2[j] - m2) * L2E); s2 += e2[j];
            e3[j] = fexp2((sc3[j] - m3) * L2E); s3 += e3[j];
        }
#pragma unroll
        for (int m = 32; m >= 1; m >>= 1) {
            s0 += __shfl_xor(s0, m, 64);
            s1 += __shfl_xor(s1, m, 64);
            s2 += __shfl_xor(s2, m, 64);
            s3 += __shfl_xor(s3, m, 64);
        }
        const float r0 = frcp(s0), r1 = frcp(s1), r2 = frcp(s2), r3 = frcp(s3);

        const float4 p0 = make_float4(e0[0] * r0, e0[1] * r0, e0[2] * r0, e0[3] * r0);
        const float4 p1 = make_float4(e1[0] * r1, e1[1] * r1, e1[2] * r1, e1[3] * r1);
        const float4 p2 = make_float4(e2[0] * r2, e2[1] * r2, e2[2] * r2, e2[3] * r2);
        const float4 p3 = make_float4(e3[0] * r3, e3[1] * r3, e3[2] * r3, e3[3] * r3);

        float* __restrict__ po = attn_out + ((size_t)b * TQ + q0) * TK + lane * 4;
        *(float4*)(po + 0 * TK) = p0;
        *(float4*)(po + 1 * TK) = p1;
        *(float4*)(po + 2 * TK) = p2;
        *(float4*)(po + 3 * TK) = p3;

        *(h16x4*)&pl[g * 4 + 0][lane * 4] = pack4h(p0);
        *(h16x4*)&pl[g * 4 + 1][lane * 4] = pack4h(p1);
        *(h16x4*)&pl[g * 4 + 2][lane * 4] = pack4h(p2);
        *(h16x4*)&pl[g * 4 + 3][lane * 4] = pack4h(p3);
    }
    __syncthreads();

    // ---- PV: wave w -> c-tile w (c0 = w*16) ----
    const int lr = lane & 15, lk = lane >> 4;
    const _Float16* __restrict__ Vr = v16s + b * 32768 + w * 4096 + lane * 8;
    f32x4 acc = {0.f, 0.f, 0.f, 0.f};
#pragma unroll
    for (int s = 0; s < 8; ++s) {
        f16x8 a = *(const f16x8*)&pl[lr][s * 32 + lk * 8];
        f16x8 bv = *(const f16x8*)(Vr + s * 512);
        acc = __builtin_amdgcn_mfma_f32_16x16x32_f16(a, bv, acc, 0, 0, 0);
    }
    float4 o = make_float4(acc[0], acc[1], acc[2], acc[3]);
    *(float4*)&out[((size_t)b * CC + w * 16 + lr) * TQ + q0g + lk * 4] = o;
}

extern "C" void kernel_launch(void* const* d_in, const int* in_sizes, int n_in,
                              void* d_out, int out_size, void* d_ws, size_t ws_size,
                              hipStream_t stream) {
    const float* queries = (const float*)d_in[0];
    const float* keys    = (const float*)d_in[1];
    const float* values  = (const float*)d_in[2];
    const float* Wq      = (const float*)d_in[3];
    const float* Wk      = (const float*)d_in[4];
    const float* Wv      = (const float*)d_in[5];
    const float* Wvec    = (const float*)d_in[6];

    float* out  = (float*)d_out;                 // (8,128,512)
    float* attn = out + BB * CC * TQ;            // (8,512,256)

    float* ws = (float*)d_ws;
    float* eqp = ws;                              // [b][t][c] 4096*128 f32
    float* ekp = eqp + 4096 * CC;                 // [b][c][t] 2048*128 f32
    _Float16* v16s = (_Float16*)(ekp + 2048 * CC);// frag-linear 8*32768
    _Float16* Wk16s = v16s + 8 * 32768;           // 81920
    _Float16* Wv16s = Wk16s + 81920;              // 81920
    _Float16* Wq16s = Wv16s + 81920;              // 12288
    _Float16* Xq16s = Wq16s + 12288;              // 393216
    _Float16* Xk16s = Xq16s + 393216;             // 1310720
    _Float16* Xv16s = Xk16s + 1310720;            // 1310720

    convert_kernel<<<dim3((CTOT + 255) / 256), 256, 0, stream>>>(
        Wk, Wv, Wq, queries, keys, values,
        (f16x8*)Wk16s, (f16x8*)Wv16s, (f16x8*)Wq16s,
        (f16x8*)Xq16s, (f16x8*)Xk16s, (f16x8*)Xv16s);
    proj_mfma<<<dim3(512), 256, 0, stream>>>(
        Wk16s, Wv16s, Wq16s, Xq16s, Xk16s, Xv16s, eqp, ekp, v16s);
    attn_pv_kernel<<<dim3(32, 8), 512, 0, stream>>>(
        eqp, ekp, Wvec, v16s, attn, out);
}